// Round 2
// baseline (1828.449 us; speedup 1.0000x reference)
//
#include <hip/hip_runtime.h>
#include <hip/hip_bf16.h>
#include <math.h>

#define LAYERS 32
#define H      1024
#define H3     3072
#define NHEADS 16
#define HDIM   64
#define FF     2048
#define BATCH  2
#define SEQ    2048
#define EPSF   1e-6f
#define NBAR   160

__constant__ int d_KIND[LAYERS] = {0,1,2,3,0,1,2,0,1,2,3,0,1,2,0,1,2,3,0,1,2,0,1,2,3,0,1,2,0,1,2,3};

__device__ __forceinline__ float wredSum(float v) {
#pragma unroll
  for (int m = 32; m >= 1; m >>= 1) v += __shfl_xor(v, m, 64);
  return v;
}
__device__ __forceinline__ float wredMax(float v) {
#pragma unroll
  for (int m = 32; m >= 1; m >>= 1) v = fmaxf(v, __shfl_xor(v, m, 64));
  return v;
}
__device__ __forceinline__ float gelu_t(float x) {
  return 0.5f * x * (1.0f + tanhf(0.7978845608028654f * (x + 0.044715f * x * x * x)));
}

struct NS   { float xe[2][1024]; float red[16]; float scl[2]; float p[6][4][2]; };
struct W2S  { float hs[2][2048]; float pr[2][8][2]; };
struct OUTS { float ys[2][1024]; float pr[2][4][2]; };
struct ATTS { float q[64]; float k[64]; float v[64]; float e[128]; float red[16]; float osum[8][64]; };
union SH { NS ns; W2S w2; OUTS o; ATTS att; };

struct MegaArgs {
  const float* x0; const int* posp;
  const float* n1; const float* n2;
  const float* pW; const float* pb; const float* oW; const float* ob;
  const float* W1; const float* W2;
  const float* sfc; const float* sfd; const float* mix0; const float* mix1;
  const float* kc; const float* vc; const float* cosT; const float* sinT;
  float* z; float* y; float* xA; float* xB; float* xM; float* h; float* attP;
  int* bar; float* out; int nwg;
};

// ---------------------------------------------------------------------------
__device__ __forceinline__ void gridbar(int* bar, int st, int wg, int nwg) {
  __syncthreads();
  if (threadIdx.x == 0) {
    int* cnt  = bar + st * 8;
    int* flag = bar + NBAR * 8 + st;
    __hip_atomic_fetch_add(&cnt[wg & 7], 1, __ATOMIC_RELEASE, __HIP_MEMORY_SCOPE_AGENT);
    if (wg == 0) {
      int s;
      do {
        s = 0;
#pragma unroll
        for (int i = 0; i < 8; i++)
          s += __hip_atomic_load(&cnt[i], __ATOMIC_RELAXED, __HIP_MEMORY_SCOPE_AGENT);
      } while (s < nwg);
      __hip_atomic_store(flag, 1, __ATOMIC_RELEASE, __HIP_MEMORY_SCOPE_AGENT);
    } else {
      while (__hip_atomic_load(flag, __ATOMIC_RELAXED, __HIP_MEMORY_SCOPE_AGENT) == 0) {}
    }
    __builtin_amdgcn_fence(__ATOMIC_ACQUIRE, "agent");
  }
  __syncthreads();
}

// ---------------------------------------------------------------------------
__device__ __forceinline__ void block_norm(const float* __restrict__ xin,
                                           const float* __restrict__ nw, SH& sh) {
  int tid = threadIdx.x, lane = tid & 63, wave = tid >> 6;
  float4 xv = ((const float4*)xin)[tid];
  int b = tid >> 8, ci = tid & 255;
  float4 nv = ((const float4*)nw)[ci];
  float ss = xv.x * xv.x + xv.y * xv.y + xv.z * xv.z + xv.w * xv.w;
  ((float4*)&sh.ns.xe[b][ci << 2])[0] =
      make_float4(xv.x * nv.x, xv.y * nv.y, xv.z * nv.z, xv.w * nv.w);
  ss = wredSum(ss);
  if (lane == 0) sh.ns.red[wave] = ss;
  __syncthreads();
  if (threadIdx.x == 0) {
    sh.ns.scl[0] = rsqrtf((sh.ns.red[0] + sh.ns.red[1] + sh.ns.red[2] + sh.ns.red[3]) * (1.0f / 1024.f) + EPSF);
    sh.ns.scl[1] = rsqrtf((sh.ns.red[4] + sh.ns.red[5] + sh.ns.red[6] + sh.ns.red[7]) * (1.0f / 1024.f) + EPSF);
  }
  __syncthreads();
}

// ---------------------------------------------------------------------------
// stage P: norm + proj GEMV. For mixer layers rows are mapped as channel
// triples (x2,x1,v) so we also produce y = (mix1*x1*v + mix0)*x2 in-block.
// For ATT layers writes raw z.
// ---------------------------------------------------------------------------
__device__ __forceinline__ void stageP(const MegaArgs& a, SH& sh, int wg, int nwg,
                                       int layer, int kind, const float* xin) {
  block_norm(xin, a.n1 + layer * H, sh);
  const float* W  = a.pW + (size_t)layer * H3 * H;
  const float* pb = a.pb + layer * H3;
  const float* sfcL = a.sfc + (size_t)layer * H3;
  const float* sfdL = a.sfd + (size_t)layer * 2 * H3;
  const float* mix0L = a.mix0 + (size_t)layer * 2 * H;
  const float* mix1L = a.mix1 + (size_t)layer * H;
  int tid = threadIdx.x, lane = tid & 63, wave = tid >> 6;
  for (int rb = wg; rb < 512; rb += nwg) {
    int n = rb >> 5, d0 = (rb & 31) << 1;
    float part[3][2];
    float4 wv[3];
#pragma unroll
    for (int k = 0; k < 3; k++) {
      int t = wave + 8 * k, j = t >> 2, ch = t & 3;
      int grow = (kind == 3) ? (rb * 6 + j) : (n * 192 + (j >> 1) * 64 + d0 + (j & 1));
      wv[k] = *(const float4*)(W + (size_t)grow * H + (ch << 8) + (lane << 2));
    }
#pragma unroll
    for (int k = 0; k < 3; k++) {
      int ch = (wave + 8 * k) & 3;
      float4 xa = *(const float4*)&sh.ns.xe[0][(ch << 8) + (lane << 2)];
      float4 xb = *(const float4*)&sh.ns.xe[1][(ch << 8) + (lane << 2)];
      part[k][0] = wv[k].x * xa.x + wv[k].y * xa.y + wv[k].z * xa.z + wv[k].w * xa.w;
      part[k][1] = wv[k].x * xb.x + wv[k].y * xb.y + wv[k].z * xb.z + wv[k].w * xb.w;
    }
#pragma unroll
    for (int k = 0; k < 3; k++) {
      float s0 = wredSum(part[k][0]);
      float s1 = wredSum(part[k][1]);
      int t = wave + 8 * k, j = t >> 2, ch = t & 3;
      if (lane == 0) { sh.ns.p[j][ch][0] = s0; sh.ns.p[j][ch][1] = s1; }
    }
    __syncthreads();
    if (wave == 0) {
      if (lane < 48) {
        int j = lane >> 3, b = (lane >> 2) & 1, ch = lane & 3;
        float v = sh.ns.p[j][ch][b];
        v += __shfl_xor(v, 1, 64);
        v += __shfl_xor(v, 2, 64);
        if (ch == 0) {
          int grow = (kind == 3) ? (rb * 6 + j) : (n * 192 + (j >> 1) * 64 + d0 + (j & 1));
          float zraw = v * sh.ns.scl[b] + pb[grow];
          if (kind == 3) {
            a.z[b * H3 + grow] = zraw;
          } else {
            sh.ns.p[j][0][b] = sfcL[grow] * zraw + sfdL[b * H3 + grow];
          }
        }
      }
      if (kind != 3 && lane < 4) {
        int q = lane & 1, b = lane >> 1;
        float x2 = sh.ns.p[0 + q][0][b];
        float x1 = sh.ns.p[2 + q][0][b];
        float vv = sh.ns.p[4 + q][0][b];
        int c = n * 64 + d0 + q;
        float t = x1 * vv;
        a.y[b * H + c] = (mix1L[c] * t + mix0L[b * H + c]) * x2;
      }
    }
    __syncthreads();
  }
}

// ---------------------------------------------------------------------------
// stage A: flash-decode partials, 512 tasks = 16 splits x 16 heads x 2 batch
// ---------------------------------------------------------------------------
__device__ __forceinline__ void stageA(const MegaArgs& a, SH& sh, int wg, int nwg, int att) {
  int tid = threadIdx.x, lane = tid & 63;
  int pos = a.posp[0];
  int ck = (pos + 16) >> 4;
  const float* kcL = a.kc + (size_t)att * BATCH * SEQ * NHEADS * HDIM;
  const float* vcL = a.vc + (size_t)att * BATCH * SEQ * NHEADS * HDIM;
  for (int task = wg; task < 512; task += nwg) {
    int sp = task & 15, n = (task >> 4) & 15, b = task >> 8;
    int s0 = sp * ck;
    int send = min(s0 + ck, pos + 1);
    if (tid < 64) {
      int d = tid, jr = d & 31;
      float cs = a.cosT[pos * 32 + jr], sn = a.sinT[pos * 32 + jr];
      float qv = a.z[b * H3 + n * 64 + d];
      float qo = a.z[b * H3 + n * 64 + ((d + 32) & 63)];
      sh.att.q[d] = ((d < 32) ? (qv * cs - qo * sn) : (qv * cs + qo * sn)) * 0.125f;
      float kv = a.z[b * H3 + 1024 + n * 64 + d];
      float ko = a.z[b * H3 + 1024 + n * 64 + ((d + 32) & 63)];
      sh.att.k[d] = (d < 32) ? (kv * cs - ko * sn) : (kv * cs + ko * sn);
      sh.att.v[d] = a.z[b * H3 + 2048 + n * 64 + d];
    }
    __syncthreads();
    int slot = tid >> 2, quarter = tid & 3;
    int p = s0 + slot;
    float lg = -1e30f;
    if (p < send) {
      const float4* k4 = (p == pos) ? (const float4*)sh.att.k
                                    : (const float4*)(kcL + (((size_t)b * SEQ + p) * NHEADS + n) * HDIM);
      const float4* q4 = (const float4*)sh.att.q;
      float acc = 0.f;
#pragma unroll
      for (int jj = 0; jj < 4; jj++) {
        float4 kk = k4[quarter * 4 + jj], qq = q4[quarter * 4 + jj];
        acc += kk.x * qq.x + kk.y * qq.y + kk.z * qq.z + kk.w * qq.w;
      }
      acc += __shfl_xor(acc, 1, 64);
      acc += __shfl_xor(acc, 2, 64);
      lg = acc;
    }
    float mw = wredMax(lg);
    if (lane == 0) sh.att.red[tid >> 6] = mw;
    __syncthreads();
    float m = sh.att.red[0];
#pragma unroll
    for (int jj = 1; jj < 8; jj++) m = fmaxf(m, sh.att.red[jj]);
    float ee = expf(lg - m);
    if (quarter == 0) sh.att.e[slot] = ee;
    float ssum = wredSum(quarter == 0 ? ee : 0.f);
    __syncthreads();
    if (lane == 0) sh.att.red[tid >> 6] = ssum;
    __syncthreads();
    float lsum = 0.f;
#pragma unroll
    for (int jj = 0; jj < 8; jj++) lsum += sh.att.red[jj];
    // PV
    int d = tid & 63, prow = tid >> 6;
    float acc2 = 0.f;
    for (int jj = prow; jj < ck; jj += 8) {
      int pp = s0 + jj;
      if (pp < send) {
        const float* vrow = (pp == pos) ? sh.att.v
                                        : (vcL + (((size_t)b * SEQ + pp) * NHEADS + n) * HDIM);
        acc2 += sh.att.e[jj] * vrow[d];
      }
    }
    sh.att.osum[prow][d] = acc2;
    __syncthreads();
    float* Pp = a.attP + (size_t)task * 66;
    if (tid < 64) {
      float o = 0.f;
#pragma unroll
      for (int jj = 0; jj < 8; jj++) o += sh.att.osum[jj][d];
      Pp[d] = o;
    } else if (tid == 64) Pp[64] = m;
    else if (tid == 65) Pp[65] = lsum;
    __syncthreads();
  }
}

// ---------------------------------------------------------------------------
// stage Out: y (or attn-combine) -> out_W GEMV + bias + residual -> xM
// ---------------------------------------------------------------------------
__device__ __forceinline__ void stageOut(const MegaArgs& a, SH& sh, int wg, int nwg,
                                         int layer, int kind, const float* xin) {
  int tid = threadIdx.x, lane = tid & 63, wave = tid >> 6;
  if (kind != 3) {
    for (int e = tid; e < 2048; e += 512) (&sh.o.ys[0][0])[e] = a.y[e];
  } else {
    for (int e = tid; e < 2048; e += 512) {
      int b = e >> 10, c = e & 1023, n = c >> 6, d = c & 63;
      const float* P = a.attP + (size_t)((b * 16 + n) * 16) * 66;
      float M = -1e30f;
#pragma unroll
      for (int sp = 0; sp < 16; sp++) M = fmaxf(M, P[sp * 66 + 64]);
      float L = 0.f, num = 0.f;
#pragma unroll
      for (int sp = 0; sp < 16; sp++) {
        float w = expf(P[sp * 66 + 64] - M);
        L += w * P[sp * 66 + 65];
        num += w * P[sp * 66 + d];
      }
      (&sh.o.ys[0][0])[e] = num / L;
    }
  }
  __syncthreads();
  const float* W  = a.oW + (size_t)layer * H * H;
  const float* ob = a.ob + layer * H;
  for (int rb = wg; rb < 512; rb += nwg) {
    int j = wave >> 2, ch = wave & 3;
    int grow = rb * 2 + j;
    float4 wv = *(const float4*)(W + (size_t)grow * H + (ch << 8) + (lane << 2));
    float4 ya = *(const float4*)&sh.o.ys[0][(ch << 8) + (lane << 2)];
    float4 yb = *(const float4*)&sh.o.ys[1][(ch << 8) + (lane << 2)];
    float p0 = wv.x * ya.x + wv.y * ya.y + wv.z * ya.z + wv.w * ya.w;
    float p1 = wv.x * yb.x + wv.y * yb.y + wv.z * yb.z + wv.w * yb.w;
    p0 = wredSum(p0); p1 = wredSum(p1);
    if (lane == 0) { sh.o.pr[j][ch][0] = p0; sh.o.pr[j][ch][1] = p1; }
    __syncthreads();
    if (wave == 0 && lane < 16) {
      int jj = lane >> 3, b = (lane >> 2) & 1, cc = lane & 3;
      float v = sh.o.pr[jj][cc][b];
      v += __shfl_xor(v, 1, 64);
      v += __shfl_xor(v, 2, 64);
      if (cc == 0) {
        int gr = rb * 2 + jj;
        a.xM[b * H + gr] = v + ob[gr] + xin[b * H + gr];
      }
    }
    __syncthreads();
  }
}

// ---------------------------------------------------------------------------
// stage W1: norm(xM) + W1 GEMV + gelu -> h
// ---------------------------------------------------------------------------
__device__ __forceinline__ void stageW1(const MegaArgs& a, SH& sh, int wg, int nwg, int layer) {
  block_norm(a.xM, a.n2 + layer * H, sh);
  const float* W = a.W1 + (size_t)layer * FF * H;
  int tid = threadIdx.x, lane = tid & 63, wave = tid >> 6;
  for (int rb = wg; rb < 512; rb += nwg) {
    float part[2][2];
    float4 wv[2];
#pragma unroll
    for (int k = 0; k < 2; k++) {
      int t = wave + 8 * k, j = t >> 2, ch = t & 3;
      wv[k] = *(const float4*)(W + (size_t)(rb * 4 + j) * H + (ch << 8) + (lane << 2));
    }
#pragma unroll
    for (int k = 0; k < 2; k++) {
      int ch = (wave + 8 * k) & 3;
      float4 xa = *(const float4*)&sh.ns.xe[0][(ch << 8) + (lane << 2)];
      float4 xb = *(const float4*)&sh.ns.xe[1][(ch << 8) + (lane << 2)];
      part[k][0] = wv[k].x * xa.x + wv[k].y * xa.y + wv[k].z * xa.z + wv[k].w * xa.w;
      part[k][1] = wv[k].x * xb.x + wv[k].y * xb.y + wv[k].z * xb.z + wv[k].w * xb.w;
    }
#pragma unroll
    for (int k = 0; k < 2; k++) {
      float s0 = wredSum(part[k][0]);
      float s1 = wredSum(part[k][1]);
      int t = wave + 8 * k, j = t >> 2, ch = t & 3;
      if (lane == 0) { sh.ns.p[j][ch][0] = s0; sh.ns.p[j][ch][1] = s1; }
    }
    __syncthreads();
    if (wave == 0 && lane < 32) {
      int j = lane >> 3, b = (lane >> 2) & 1, ch = lane & 3;
      float v = sh.ns.p[j][ch][b];
      v += __shfl_xor(v, 1, 64);
      v += __shfl_xor(v, 2, 64);
      if (ch == 0) a.h[b * FF + rb * 4 + j] = gelu_t(v * sh.ns.scl[b]);
    }
    __syncthreads();
  }
}

// ---------------------------------------------------------------------------
// stage W2: W2 GEMV (K=2048) + residual -> xout
// ---------------------------------------------------------------------------
__device__ __forceinline__ void stageW2(const MegaArgs& a, SH& sh, int wg, int nwg,
                                        int layer, float* xout) {
  int tid = threadIdx.x, lane = tid & 63, wave = tid >> 6;
  for (int e = tid; e < 4096; e += 512) (&sh.w2.hs[0][0])[e] = a.h[e];
  __syncthreads();
  const float* W = a.W2 + (size_t)layer * H * FF;
  for (int rb = wg; rb < 512; rb += nwg) {
    float part[2][2];
    float4 wv[2];
#pragma unroll
    for (int k = 0; k < 2; k++) {
      int t = wave + 8 * k, j = t >> 3, ch = t & 7;
      wv[k] = *(const float4*)(W + (size_t)(rb * 2 + j) * FF + (ch << 8) + (lane << 2));
    }
#pragma unroll
    for (int k = 0; k < 2; k++) {
      int ch = (wave + 8 * k) & 7;
      float4 ha = *(const float4*)&sh.w2.hs[0][(ch << 8) + (lane << 2)];
      float4 hb = *(const float4*)&sh.w2.hs[1][(ch << 8) + (lane << 2)];
      part[k][0] = wv[k].x * ha.x + wv[k].y * ha.y + wv[k].z * ha.z + wv[k].w * ha.w;
      part[k][1] = wv[k].x * hb.x + wv[k].y * hb.y + wv[k].z * hb.z + wv[k].w * hb.w;
    }
#pragma unroll
    for (int k = 0; k < 2; k++) {
      float s0 = wredSum(part[k][0]);
      float s1 = wredSum(part[k][1]);
      int t = wave + 8 * k, j = t >> 3, ch = t & 7;
      if (lane == 0) { sh.w2.pr[j][ch][0] = s0; sh.w2.pr[j][ch][1] = s1; }
    }
    __syncthreads();
    if (wave == 0 && lane < 32) {
      int j = lane >> 4, b = (lane >> 3) & 1, ch = lane & 7;
      float v = sh.w2.pr[j][ch][b];
      v += __shfl_xor(v, 1, 64);
      v += __shfl_xor(v, 2, 64);
      v += __shfl_xor(v, 4, 64);
      if (ch == 0) {
        int gr = rb * 2 + j;
        xout[b * H + gr] = v + a.xM[b * H + gr];
      }
    }
    __syncthreads();
  }
}

// ---------------------------------------------------------------------------
__global__ __launch_bounds__(512, 4) void mega(MegaArgs a) {
  __shared__ SH sh;
  int wg = blockIdx.x, nwg = a.nwg;
  int st = 0;
  const float* xin = a.x0;
  int att = 0;
  for (int i = 0; i < LAYERS; i++) {
    int kind = d_KIND[i];
    stageP(a, sh, wg, nwg, i, kind, xin);
    gridbar(a.bar, st++, wg, nwg);
    if (kind == 3) {
      stageA(a, sh, wg, nwg, att);
      gridbar(a.bar, st++, wg, nwg);
      att++;
    }
    stageOut(a, sh, wg, nwg, i, kind, xin);
    gridbar(a.bar, st++, wg, nwg);
    stageW1(a, sh, wg, nwg, i);
    gridbar(a.bar, st++, wg, nwg);
    float* xout = (i == LAYERS - 1) ? a.out : ((i & 1) ? a.xB : a.xA);
    stageW2(a, sh, wg, nwg, i, xout);
    if (i != LAYERS - 1) gridbar(a.bar, st++, wg, nwg);
    xin = xout;
  }
}

// ---------------------------------------------------------------------------
// prep: hoist state-linear terms (unchanged, verified) + zero barrier area
// ---------------------------------------------------------------------------
__global__ __launch_bounds__(256) void prep_kernel(
    const float* __restrict__ sf_w, const float* __restrict__ sf_b,
    const float* __restrict__ fir_state,
    const float* __restrict__ hcs_h, const float* __restrict__ hcs_D, const float* __restrict__ hcs_state,
    const float* __restrict__ hcm_h, const float* __restrict__ hcm_D, const float* __restrict__ hcm_state,
    const float* __restrict__ lp, const float* __restrict__ resd, const float* __restrict__ hcl_D,
    const float* __restrict__ iir,
    unsigned long long kbits,
    float* __restrict__ sfd, float* __restrict__ sfc,
    float* __restrict__ mix0, float* __restrict__ mix1, int* __restrict__ bar)
{
  int blk = blockIdx.x, tid = threadIdx.x;
  if (blk < 768) {
    int idx = blk * 256 + tid;
    int i = idx / (BATCH * H3);
    int r = idx % (BATCH * H3);
    int b = r / H3, ch = r % H3;
    const float* fs = fir_state + ((size_t)(i * BATCH + b) * H3 + ch) * 2;
    const float* sw = sf_w + ((size_t)i * H3 + ch) * 3;
    sfd[idx] = fs[0] * sw[0] + fs[1] * sw[1] + sf_b[i * H3 + ch];
    if (b == 0) sfc[i * H3 + ch] = sw[2];
  } else if (blk < 1024) {
    int idx = (blk - 768) * 256 + tid;
    int i = idx >> 11;
    int r = idx & 2047;
    int b = r >> 10, c = r & 1023;
    int kind = (int)((kbits >> (2 * i)) & 3ull);
    if (kind == 0) {
      const float* st = hcs_state + ((size_t)(i * BATCH + b) * H + c) * 6;
      const float* hh = hcs_h + ((size_t)i * H + c) * 7;
      float acc = 0.f;
#pragma unroll
      for (int k = 0; k < 6; k++) acc += st[k] * hh[k];
      mix0[idx] = acc + hcs_D[i * H + c];
      if (b == 0) mix1[i * H + c] = hh[6];
    } else if (kind == 2) {
      const float* ii = iir + ((size_t)(i * BATCH + b) * H + c) * 16;
      const float* lpp = lp + ((size_t)i * H + c) * 16;
      const float* rs = resd + ((size_t)i * H + c) * 16;
      float acc = 0.f, rsum = 0.f;
#pragma unroll
      for (int k = 0; k < 16; k++) { float rv = rs[k]; acc += rv * expf(lpp[k]) * ii[k]; rsum += rv; }
      mix0[idx] = acc;
      if (b == 0) mix1[i * H + c] = rsum + hcl_D[i * H + c];
    }
  } else if (blk < 5632) {
    int w = tid >> 6, lane = tid & 63;
    int widx = (blk - 1024) * 4 + w;
    if (widx < 9 * BATCH * H) {
      int li = widx >> 11;
      int r = widx & 2047;
      int b = r >> 10, c = r & 1023;
      int i = (li >> 1) * 7 + ((li & 1) ? 5 : 1);
      const float* st = hcm_state + ((size_t)(i * BATCH + b) * H + c) * 127;
      const float* hh = hcm_h + ((size_t)i * H + c) * 128;
      float acc = 0.f;
      int k = lane;
      if (k < 127) acc += st[k] * hh[127 - k];
      k = lane + 64;
      if (k < 127) acc += st[k] * hh[127 - k];
      acc = wredSum(acc);
      if (lane == 0) {
        mix0[(i * BATCH + b) * H + c] = acc;
        if (b == 0) mix1[i * H + c] = hh[0] + hcm_D[i * H + c];
      }
    }
  } else {
    for (int j = tid; j < NBAR * 9; j += 256) bar[j] = 0;
  }
}

// ---------------------------------------------------------------------------
extern "C" void kernel_launch(void* const* d_in, const int* in_sizes, int n_in,
                              void* d_out, int out_size, void* d_ws, size_t ws_size,
                              hipStream_t stream) {
  (void)in_sizes; (void)n_in; (void)out_size; (void)ws_size;
  const float* x0    = (const float*)d_in[0];
  const int*   posp  = (const int*)d_in[1];
  const float* n1    = (const float*)d_in[2];
  const float* n2    = (const float*)d_in[3];
  const float* pW    = (const float*)d_in[4];
  const float* pb    = (const float*)d_in[5];
  const float* oW    = (const float*)d_in[6];
  const float* ob    = (const float*)d_in[7];
  const float* W1    = (const float*)d_in[8];
  const float* W2    = (const float*)d_in[9];
  const float* sfw   = (const float*)d_in[10];
  const float* sfb   = (const float*)d_in[11];
  const float* hcs_h = (const float*)d_in[12];
  const float* hcs_D = (const float*)d_in[13];
  const float* hcm_h = (const float*)d_in[14];
  const float* hcm_D = (const float*)d_in[15];
  const float* lp    = (const float*)d_in[16];
  const float* resd  = (const float*)d_in[17];
  const float* hclD  = (const float*)d_in[18];
  const float* fir   = (const float*)d_in[19];
  const float* hcsS  = (const float*)d_in[20];
  const float* hcmS  = (const float*)d_in[21];
  const float* iir   = (const float*)d_in[22];
  const float* kc    = (const float*)d_in[23];
  const float* vc    = (const float*)d_in[24];
  const float* cosT  = (const float*)d_in[25];
  const float* sinT  = (const float*)d_in[26];

  float* ws   = (float*)d_ws;
  float* xA   = ws;                  // 2048
  float* xB   = ws + 2048;           // 2048
  float* xM   = ws + 4096;           // 2048
  float* zb   = ws + 6144;           // 6144
  float* yb   = ws + 12288;          // 2048
  float* hb   = ws + 14336;          // 4096
  float* attP = ws + 18432;          // 33792
  float* sfd  = ws + 52224;          // 196608
  float* sfc  = ws + 248832;         // 98304
  float* mix0 = ws + 347136;         // 65536
  float* mix1 = ws + 412672;         // 32768
  int*   bar  = (int*)(ws + 445440); // 1440 ints

  static const int KIND[LAYERS] = {0,1,2,3,0,1,2,0,1,2,3,0,1,2,0,1,2,3,0,1,2,0,1,2,3,0,1,2,0,1,2,3};
  unsigned long long kbits = 0ull;
  for (int i = 0; i < LAYERS; i++) kbits |= ((unsigned long long)KIND[i]) << (2 * i);

  prep_kernel<<<5633, 256, 0, stream>>>(sfw, sfb, fir, hcs_h, hcs_D, hcsS,
      hcm_h, hcm_D, hcmS, lp, resd, hclD, iir, kbits, sfd, sfc, mix0, mix1, bar);

  int occ = 0;
  hipError_t oe = hipOccupancyMaxActiveBlocksPerMultiprocessor(&occ, mega, 512, 0);
  if (oe != hipSuccess || occ < 1) occ = 1;
  int nwg = occ * 256;
  if (nwg > 512) nwg = 512;

  MegaArgs ma;
  ma.x0 = x0; ma.posp = posp; ma.n1 = n1; ma.n2 = n2;
  ma.pW = pW; ma.pb = pb; ma.oW = oW; ma.ob = ob; ma.W1 = W1; ma.W2 = W2;
  ma.sfc = sfc; ma.sfd = sfd; ma.mix0 = mix0; ma.mix1 = mix1;
  ma.kc = kc; ma.vc = vc; ma.cosT = cosT; ma.sinT = sinT;
  ma.z = zb; ma.y = yb; ma.xA = xA; ma.xB = xB; ma.xM = xM; ma.h = hb; ma.attP = attP;
  ma.bar = bar; ma.out = (float*)d_out; ma.nwg = nwg;

  void* kp[] = { &ma };
  hipLaunchCooperativeKernel(mega, dim3(nwg), dim3(512), kp, 0, stream);
}